// Round 8
// baseline (1341.047 us; speedup 1.0000x reference)
//
#include <hip/hip_runtime.h>
#include <hip/hip_fp16.h>
#include <cmath>

constexpr int D   = 96;
constexpr int C   = 12;
constexpr int P   = 11;   // 1 + 2*5
constexpr int VOX = D * D * D;        // 884736
constexpr int CELLS = 32 * 32 * 32;   // Morton 32^3 sort buckets

// ---------------------------------------------------------------------------
// Morton cell key
// ---------------------------------------------------------------------------
__device__ __forceinline__ unsigned spread5(unsigned v) {
  v &= 31u;
  v = (v | (v << 8)) & 0x100Fu;
  v = (v | (v << 4)) & 0x10C3u;
  v = (v | (v << 2)) & 0x1249u;
  return v;
}

__device__ __forceinline__ unsigned cell_of_u(const float u[3]) {
  unsigned cc[3];
#pragma unroll
  for (int d = 0; d < 3; ++d) {
    int c = (int)((u[d] + 1.0f) * 16.0f);
    c = c < 0 ? 0 : (c > 31 ? 31 : c);
    cc[d] = (unsigned)c;
  }
  return spread5(cc[0]) | (spread5(cc[1]) << 1) | (spread5(cc[2]) << 2);
}

__device__ __forceinline__ void norm_u(const float* __restrict__ xyz, int n,
                                       const float* __restrict__ mn,
                                       const float* __restrict__ mx, float u[3]) {
#pragma unroll
  for (int d = 0; d < 3; ++d)
    u[d] = (xyz[3 * (size_t)n + d] - mn[d]) * (2.0f / (mx[d] - mn[d])) - 1.0f;
}

// ---------------------------------------------------------------------------
// Transpose+downconvert [P*C][x][y][z] f32 -> [P][x][y][z][C] fp16, with the
// histogram count fused in (threads t < N also bin their point).
// ---------------------------------------------------------------------------
__global__ __launch_bounds__(256) void transpose_count_kernel(
    const float* __restrict__ g, __half* __restrict__ gt,
    const float* __restrict__ xyz, const float* __restrict__ mn,
    const float* __restrict__ mx, unsigned* __restrict__ counts, int N) {
  constexpr int RPT = VOX / 4;
  int t = blockIdx.x * 256 + threadIdx.x;

  if (t < P * RPT) {
    int p = t / RPT;
    int r4 = (t - p * RPT) * 4;
    const float* src = g + (size_t)p * C * VOX + r4;
    float4 v[C];
#pragma unroll
    for (int c = 0; c < C; ++c)
      v[c] = *reinterpret_cast<const float4*>(src + (size_t)c * VOX);
    union { __half h[48]; uint4 u[6]; } pk;
#pragma unroll
    for (int j = 0; j < 4; ++j) {
#pragma unroll
      for (int c = 0; c < C; ++c) {
        float f = (j == 0) ? v[c].x : (j == 1) ? v[c].y : (j == 2) ? v[c].z : v[c].w;
        pk.h[j * C + c] = __float2half_rn(f);
      }
    }
    uint4* dst = reinterpret_cast<uint4*>(gt + ((size_t)p * VOX + r4) * C);
#pragma unroll
    for (int k = 0; k < 6; ++k) dst[k] = pk.u[k];
  }

  if (t < N) {
    float u[3];
    norm_u(xyz, t, mn, mx, u);
    atomicAdd(&counts[cell_of_u(u)], 1u);
  }
}

// Single-block exclusive scan of CELLS (=32768) counters.
__global__ __launch_bounds__(1024) void scan_kernel(
    const unsigned* __restrict__ counts, unsigned* __restrict__ offsets) {
  __shared__ unsigned part[1024];
  int t = threadIdx.x;
  unsigned base = t * (CELLS / 1024);
  unsigned local[CELLS / 1024];
  unsigned s = 0;
#pragma unroll
  for (int i = 0; i < CELLS / 1024; ++i) { local[i] = s; s += counts[base + i]; }
  part[t] = s;
  __syncthreads();
  for (int off = 1; off < 1024; off <<= 1) {
    unsigned v = (t >= off) ? part[t - off] : 0u;
    __syncthreads();
    part[t] += v;
    __syncthreads();
  }
  unsigned prev = (t == 0) ? 0u : part[t - 1];
#pragma unroll
  for (int i = 0; i < CELLS / 1024; ++i) offsets[base + i] = prev + local[i];
}

// Scatter normalized points into cell-sorted order: rec = {ux,uy,uz,idx}.
__global__ __launch_bounds__(256) void scatter_kernel(
    const float* __restrict__ xyz, const float* __restrict__ mn,
    const float* __restrict__ mx, unsigned* __restrict__ offsets,
    float4* __restrict__ sorted, int N) {
  int n = blockIdx.x * 256 + threadIdx.x;
  if (n >= N) return;
  float u[3];
  norm_u(xyz, n, mn, mx, u);
  unsigned slot = atomicAdd(&offsets[cell_of_u(u)], 1u);
  float4 rec;
  rec.x = u[0]; rec.y = u[1]; rec.z = u[2];
  rec.w = __uint_as_float((unsigned)n);
  sorted[slot] = rec;
}

// ---------------------------------------------------------------------------
// Sample kernel, tuned for the 64-VGPR occupancy cliff (8 waves/SIMD).
// Rolling 3-region issue: 9 quads in flight; 4th region issued while the
// 1st is consumed. 32-bit byte offsets (SGPR base + voffset) to cut address
// register pressure. One point per thread, spatially sorted order.
// ---------------------------------------------------------------------------
__global__ __launch_bounds__(256, 8) void sample_sorted_kernel(
    const float4* __restrict__ pts, const __half* __restrict__ g,
    float* __restrict__ out, int N) {
  // XCD-bijective chunked block swizzle.
  unsigned nwg = gridDim.x, bid = blockIdx.x;
  unsigned q = nwg / 8u, r = nwg % 8u;
  unsigned xcd = bid % 8u, j = bid / 8u;
  unsigned swz = (xcd < r ? xcd * (q + 1u) : r * (q + 1u) + (xcd - r) * q) + j;
  int n = (int)(swz * 256u + threadIdx.x);
  if (n >= N) return;

  float4 rec = pts[n];
  float u[3] = {rec.x, rec.y, rec.z};

  float acc[C];
#pragma unroll
  for (int c = 0; c < C; ++c) acc[c] = 0.0f;

  const char* gb = reinterpret_cast<const char*>(g);
  int p = 0;

  auto gather = [&](float ex, float ey, float ez) {
    float tz = (ez + 1.0f) * (0.5f * (D - 1));
    float ty = (ey + 1.0f) * (0.5f * (D - 1));
    float tx = (ex + 1.0f) * (0.5f * (D - 1));
    int z0 = (int)floorf(tz); z0 = z0 < 0 ? 0 : (z0 > D - 1 ? D - 1 : z0);
    int y0 = (int)floorf(ty); y0 = y0 < 0 ? 0 : (y0 > D - 1 ? D - 1 : y0);
    int x0 = (int)floorf(tx); x0 = x0 < 0 ? 0 : (x0 > D - 1 ? D - 1 : x0);
    int y1 = y0 + 1 > D - 1 ? D - 1 : y0 + 1;
    int x1 = x0 + 1 > D - 1 ? D - 1 : x0 + 1;
    float wz = tz - (float)z0, wy = ty - (float)y0, wx = tx - (float)x0;
    float wz0 = 1.0f - wz, wz1 = wz;
    float wy0 = 1.0f - wy, wy1 = wy;
    float wx0 = 1.0f - wx, wx1 = wx;

    // 32-bit byte offsets into the fp16 grid (233 MB < 4 GB).
    unsigned pb = (unsigned)p * (unsigned)VOX;
    unsigned o00 = (pb + (unsigned)((x0 * D + y0) * D + z0)) * 24u;
    unsigned o01 = (pb + (unsigned)((x0 * D + y1) * D + z0)) * 24u;
    unsigned o10 = (pb + (unsigned)((x1 * D + y0) * D + z0)) * 24u;
    unsigned o11 = (pb + (unsigned)((x1 * D + y1) * D + z0)) * 24u;

    auto consume = [&](const uint4& q0, const uint4& q1, const uint4& q2,
                       float wxy) {
      float w0 = wxy * wz0, w1 = wxy * wz1;
      auto acc2 = [&](unsigned lo, unsigned hi, int c) {
        __half2 hl = *reinterpret_cast<const __half2*>(&lo);
        __half2 hh = *reinterpret_cast<const __half2*>(&hi);
        float2 f0 = __half22float2(hl);
        float2 f1 = __half22float2(hh);
        acc[c]     = fmaf(w0, f0.x, fmaf(w1, f1.x, acc[c]));
        acc[c + 1] = fmaf(w0, f0.y, fmaf(w1, f1.y, acc[c + 1]));
      };
      acc2(q0.x, q1.z, 0);
      acc2(q0.y, q1.w, 2);
      acc2(q0.z, q2.x, 4);
      acc2(q0.w, q2.y, 6);
      acc2(q1.x, q2.z, 8);
      acc2(q1.y, q2.w, 10);
    };

    // Rolling issue: 3 regions (9 quads) in flight, 4th issued after the
    // 1st is consumed. (z0==95 overread is weight-0 and stays in-bounds.)
    uint4 a0 = *reinterpret_cast<const uint4*>(gb + o00);
    uint4 a1 = *reinterpret_cast<const uint4*>(gb + o00 + 16);
    uint4 a2 = *reinterpret_cast<const uint4*>(gb + o00 + 32);
    uint4 b0 = *reinterpret_cast<const uint4*>(gb + o01);
    uint4 b1 = *reinterpret_cast<const uint4*>(gb + o01 + 16);
    uint4 b2 = *reinterpret_cast<const uint4*>(gb + o01 + 32);
    uint4 c0 = *reinterpret_cast<const uint4*>(gb + o10);
    uint4 c1 = *reinterpret_cast<const uint4*>(gb + o10 + 16);
    uint4 c2 = *reinterpret_cast<const uint4*>(gb + o10 + 32);

    consume(a0, a1, a2, wx0 * wy0);

    uint4 d0 = *reinterpret_cast<const uint4*>(gb + o11);
    uint4 d1 = *reinterpret_cast<const uint4*>(gb + o11 + 16);
    uint4 d2 = *reinterpret_cast<const uint4*>(gb + o11 + 32);

    consume(b0, b1, b2, wx0 * wy1);
    consume(c0, c1, c2, wx1 * wy0);
    consume(d0, d1, d2, wx1 * wy1);
    ++p;
  };

  gather(u[0], u[1], u[2]);                       // p=0 identity

  float s[3], co[3];
#pragma unroll
  for (int d = 0; d < 3; ++d) { s[d] = sinf(u[d]); co[d] = cosf(u[d]); }
  for (int f = 0; f < 5; ++f) {                   // f = 1,2,4,8,16
    gather(s[0], s[1], s[2]);
    gather(co[0], co[1], co[2]);
    if (f < 4) {
#pragma unroll
      for (int d = 0; d < 3; ++d) {
        float ns = 2.0f * s[d] * co[d];
        float nc = 1.0f - 2.0f * s[d] * s[d];
        s[d] = ns; co[d] = nc;
      }
    }
  }

  constexpr float inv = 1.0f / (float)P;
  float4 r0, r1, r2;
  r0.x = acc[0] * inv;  r0.y = acc[1] * inv;  r0.z = acc[2] * inv;  r0.w = acc[3] * inv;
  r1.x = acc[4] * inv;  r1.y = acc[5] * inv;  r1.z = acc[6] * inv;  r1.w = acc[7] * inv;
  r2.x = acc[8] * inv;  r2.y = acc[9] * inv;  r2.z = acc[10] * inv; r2.w = acc[11] * inv;
  unsigned oidx = __float_as_uint(rec.w);
  float4* o4 = reinterpret_cast<float4*>(out + (size_t)oidx * C);
  o4[0] = r0; o4[1] = r1; o4[2] = r2;
}

// ---------------------------------------------------------------------------
// Fallback: unsorted fp16 path.
// ---------------------------------------------------------------------------
__global__ __launch_bounds__(256) void sample_fp16_kernel(
    const float* __restrict__ xyz, const __half* __restrict__ g,
    const float* __restrict__ xyz_min, const float* __restrict__ xyz_max,
    float* __restrict__ out, int N) {
  int n = blockIdx.x * 256 + threadIdx.x;
  if (n >= N) return;
  float u[3];
#pragma unroll
  for (int d = 0; d < 3; ++d) {
    float mn = xyz_min[d], mx = xyz_max[d];
    u[d] = (xyz[3 * (size_t)n + d] - mn) * (2.0f / (mx - mn)) - 1.0f;
  }
  float acc[C];
#pragma unroll
  for (int c = 0; c < C; ++c) acc[c] = 0.0f;
  const ushort* gu = reinterpret_cast<const ushort*>(g);
  int p = 0;
  auto gather = [&](float ex, float ey, float ez) {
    float tz = (ez + 1.0f) * (0.5f * (D - 1));
    float ty = (ey + 1.0f) * (0.5f * (D - 1));
    float tx = (ex + 1.0f) * (0.5f * (D - 1));
    int z0 = (int)floorf(tz); z0 = z0 < 0 ? 0 : (z0 > D - 1 ? D - 1 : z0);
    int y0 = (int)floorf(ty); y0 = y0 < 0 ? 0 : (y0 > D - 1 ? D - 1 : y0);
    int x0 = (int)floorf(tx); x0 = x0 < 0 ? 0 : (x0 > D - 1 ? D - 1 : x0);
    int y1 = y0 + 1 > D - 1 ? D - 1 : y0 + 1;
    int x1 = x0 + 1 > D - 1 ? D - 1 : x0 + 1;
    float wz = tz - (float)z0, wy = ty - (float)y0, wx = tx - (float)x0;
    float wz0 = 1.0f - wz, wz1 = wz;
    float wy0 = 1.0f - wy, wy1 = wy;
    float wx0 = 1.0f - wx, wx1 = wx;
    size_t pbase = (size_t)p * VOX;
    const uint4* r00 = reinterpret_cast<const uint4*>(gu + (pbase + (size_t)((x0 * D + y0) * D + z0)) * C);
    const uint4* r01 = reinterpret_cast<const uint4*>(gu + (pbase + (size_t)((x0 * D + y1) * D + z0)) * C);
    const uint4* r10 = reinterpret_cast<const uint4*>(gu + (pbase + (size_t)((x1 * D + y0) * D + z0)) * C);
    const uint4* r11 = reinterpret_cast<const uint4*>(gu + (pbase + (size_t)((x1 * D + y1) * D + z0)) * C);
    uint4 a0 = r00[0], a1 = r00[1], a2 = r00[2];
    uint4 b0 = r01[0], b1 = r01[1], b2 = r01[2];
    uint4 c0 = r10[0], c1 = r10[1], c2 = r10[2];
    uint4 d0 = r11[0], d1 = r11[1], d2 = r11[2];
    auto acc2 = [&](unsigned lo, unsigned hi, float w0, float w1, int c) {
      __half2 hl = *reinterpret_cast<const __half2*>(&lo);
      __half2 hh = *reinterpret_cast<const __half2*>(&hi);
      float2 f0 = __half22float2(hl);
      float2 f1 = __half22float2(hh);
      acc[c]     = fmaf(w0, f0.x, fmaf(w1, f1.x, acc[c]));
      acc[c + 1] = fmaf(w0, f0.y, fmaf(w1, f1.y, acc[c + 1]));
    };
    auto region = [&](const uint4& q0, const uint4& q1, const uint4& q2, float wxy) {
      float w0 = wxy * wz0, w1 = wxy * wz1;
      acc2(q0.x, q1.z, w0, w1, 0);
      acc2(q0.y, q1.w, w0, w1, 2);
      acc2(q0.z, q2.x, w0, w1, 4);
      acc2(q0.w, q2.y, w0, w1, 6);
      acc2(q1.x, q2.z, w0, w1, 8);
      acc2(q1.y, q2.w, w0, w1, 10);
    };
    region(a0, a1, a2, wx0 * wy0);
    region(b0, b1, b2, wx0 * wy1);
    region(c0, c1, c2, wx1 * wy0);
    region(d0, d1, d2, wx1 * wy1);
    ++p;
  };
  gather(u[0], u[1], u[2]);
  float s[3], co[3];
#pragma unroll
  for (int d = 0; d < 3; ++d) { s[d] = sinf(u[d]); co[d] = cosf(u[d]); }
  for (int f = 0; f < 5; ++f) {
    gather(s[0], s[1], s[2]);
    gather(co[0], co[1], co[2]);
    if (f < 4) {
#pragma unroll
      for (int d = 0; d < 3; ++d) {
        float ns = 2.0f * s[d] * co[d];
        float nc = 1.0f - 2.0f * s[d] * s[d];
        s[d] = ns; co[d] = nc;
      }
    }
  }
  constexpr float inv = 1.0f / (float)P;
  float4 r0, r1, r2;
  r0.x = acc[0] * inv;  r0.y = acc[1] * inv;  r0.z = acc[2] * inv;  r0.w = acc[3] * inv;
  r1.x = acc[4] * inv;  r1.y = acc[5] * inv;  r1.z = acc[6] * inv;  r1.w = acc[7] * inv;
  r2.x = acc[8] * inv;  r2.y = acc[9] * inv;  r2.z = acc[10] * inv; r2.w = acc[11] * inv;
  float4* o4 = reinterpret_cast<float4*>(out + (size_t)n * C);
  o4[0] = r0; o4[1] = r1; o4[2] = r2;
}

// Last-resort naive fp32 path.
__global__ __launch_bounds__(256) void sample_naive_kernel(
    const float* __restrict__ xyz, const float* __restrict__ g,
    const float* __restrict__ xyz_min, const float* __restrict__ xyz_max,
    float* __restrict__ out, int N) {
  int n = blockIdx.x * 256 + threadIdx.x;
  if (n >= N) return;
  float u[3];
#pragma unroll
  for (int d = 0; d < 3; ++d) {
    float mn = xyz_min[d], mx = xyz_max[d];
    u[d] = (xyz[3 * (size_t)n + d] - mn) * (2.0f / (mx - mn)) - 1.0f;
  }
  float acc[C];
#pragma unroll
  for (int c = 0; c < C; ++c) acc[c] = 0.0f;
  int p = 0;
  auto gather = [&](float ex, float ey, float ez) {
    float e[3] = {ez, ey, ex};
    int i0[3], i1[3]; float w[3];
#pragma unroll
    for (int d = 0; d < 3; ++d) {
      float t = (e[d] + 1.0f) * (0.5f * (D - 1));
      int a = (int)floorf(t);
      a = a < 0 ? 0 : (a > D - 1 ? D - 1 : a);
      int b = a + 1 > D - 1 ? D - 1 : a + 1;
      i0[d] = a; i1[d] = b; w[d] = t - (float)a;
    }
    const float* gp = g + (size_t)p * C * VOX;
    auto corner = [&](int iz, int iy, int ix, float wgt) {
      int o = (ix * D + iy) * D + iz;
#pragma unroll
      for (int c = 0; c < C; ++c) acc[c] += wgt * gp[(size_t)c * VOX + o];
    };
    corner(i0[0], i0[1], i0[2], (1 - w[0]) * (1 - w[1]) * (1 - w[2]));
    corner(i1[0], i0[1], i0[2], w[0] * (1 - w[1]) * (1 - w[2]));
    corner(i0[0], i1[1], i0[2], (1 - w[0]) * w[1] * (1 - w[2]));
    corner(i1[0], i1[1], i0[2], w[0] * w[1] * (1 - w[2]));
    corner(i0[0], i0[1], i1[2], (1 - w[0]) * (1 - w[1]) * w[2]);
    corner(i1[0], i0[1], i1[2], w[0] * (1 - w[1]) * w[2]);
    corner(i0[0], i1[1], i1[2], (1 - w[0]) * w[1] * w[2]);
    corner(i1[0], i1[1], i1[2], w[0] * w[1] * w[2]);
    ++p;
  };
  gather(u[0], u[1], u[2]);
  float s[3], co[3];
#pragma unroll
  for (int d = 0; d < 3; ++d) { s[d] = sinf(u[d]); co[d] = cosf(u[d]); }
  for (int f = 0; f < 5; ++f) {
    gather(s[0], s[1], s[2]);
    gather(co[0], co[1], co[2]);
    if (f < 4) {
#pragma unroll
      for (int d = 0; d < 3; ++d) {
        float ns = 2.0f * s[d] * co[d];
        float nc = 1.0f - 2.0f * s[d] * s[d];
        s[d] = ns; co[d] = nc;
      }
    }
  }
  constexpr float inv = 1.0f / (float)P;
#pragma unroll
  for (int c = 0; c < C; ++c) out[(size_t)n * C + c] = acc[c] * inv;
}

extern "C" void kernel_launch(void* const* d_in, const int* in_sizes, int n_in,
                              void* d_out, int out_size, void* d_ws, size_t ws_size,
                              hipStream_t stream) {
  const float* xyz = (const float*)d_in[0];
  const float* grid = (const float*)d_in[1];
  const float* mn = (const float*)d_in[2];
  const float* mx = (const float*)d_in[3];
  float* out = (float*)d_out;
  int N = in_sizes[0] / 3;

  size_t gt_bytes = (size_t)P * VOX * C * sizeof(__half);   // ~233.6 MB
  size_t sorted_bytes = (size_t)N * sizeof(float4);         // 12.8 MB
  size_t cnt_bytes = (size_t)CELLS * sizeof(unsigned);      // 128 KB

  size_t need_sorted = sorted_bytes + gt_bytes + 2 * cnt_bytes + 1024;
  size_t need_min = gt_bytes + 256;

  int sblocks = (N + 255) / 256;
  int tblocks = (P * (VOX / 4) + 255) / 256;   // covers N too (2.43M > 800k)

  if (ws_size >= need_sorted) {
    char* w = (char*)d_ws;
    float4*   sorted  = (float4*)w;   w += sorted_bytes;
    __half*   gt      = (__half*)w;   w += gt_bytes;
    unsigned* counts  = (unsigned*)w; w += cnt_bytes;
    unsigned* offsets = (unsigned*)w;

    hipMemsetAsync(counts, 0, cnt_bytes, stream);
    transpose_count_kernel<<<tblocks, 256, 0, stream>>>(grid, gt, xyz, mn, mx,
                                                        counts, N);
    scan_kernel<<<1, 1024, 0, stream>>>(counts, offsets);
    scatter_kernel<<<sblocks, 256, 0, stream>>>(xyz, mn, mx, offsets, sorted, N);
    sample_sorted_kernel<<<sblocks, 256, 0, stream>>>(sorted, gt, out, N);
  } else if (ws_size >= need_min) {
    __half* gt = (__half*)d_ws;
    transpose_count_kernel<<<tblocks, 256, 0, stream>>>(grid, gt, xyz, mn, mx,
                                                        nullptr, 0);
    sample_fp16_kernel<<<sblocks, 256, 0, stream>>>(xyz, gt, mn, mx, out, N);
  } else {
    sample_naive_kernel<<<sblocks, 256, 0, stream>>>(xyz, grid, mn, mx, out, N);
  }
}

// Round 9
// 570.952 us; speedup vs baseline: 2.3488x; 2.3488x over previous
//
#include <hip/hip_runtime.h>
#include <hip/hip_fp16.h>
#include <cmath>

constexpr int D   = 96;
constexpr int C   = 12;
constexpr int P   = 11;   // 1 + 2*5
constexpr int VOX = D * D * D;        // 884736
constexpr int CELLS = 32 * 32 * 32;   // Morton 32^3 sort buckets

// ---------------------------------------------------------------------------
// Morton cell key
// ---------------------------------------------------------------------------
__device__ __forceinline__ unsigned spread5(unsigned v) {
  v &= 31u;
  v = (v | (v << 8)) & 0x100Fu;
  v = (v | (v << 4)) & 0x10C3u;
  v = (v | (v << 2)) & 0x1249u;
  return v;
}

__device__ __forceinline__ unsigned cell_of_u(const float u[3]) {
  unsigned cc[3];
#pragma unroll
  for (int d = 0; d < 3; ++d) {
    int c = (int)((u[d] + 1.0f) * 16.0f);
    c = c < 0 ? 0 : (c > 31 ? 31 : c);
    cc[d] = (unsigned)c;
  }
  return spread5(cc[0]) | (spread5(cc[1]) << 1) | (spread5(cc[2]) << 2);
}

__device__ __forceinline__ void norm_u(const float* __restrict__ xyz, int n,
                                       const float* __restrict__ mn,
                                       const float* __restrict__ mx, float u[3]) {
#pragma unroll
  for (int d = 0; d < 3; ++d)
    u[d] = (xyz[3 * (size_t)n + d] - mn[d]) * (2.0f / (mx[d] - mn[d])) - 1.0f;
}

// ---------------------------------------------------------------------------
// Transpose+downconvert [P*C][x][y][z] f32 -> [P][x][y][z][C] fp16, with the
// histogram count fused in (threads t < N also bin their point).
// ---------------------------------------------------------------------------
__global__ __launch_bounds__(256) void transpose_count_kernel(
    const float* __restrict__ g, __half* __restrict__ gt,
    const float* __restrict__ xyz, const float* __restrict__ mn,
    const float* __restrict__ mx, unsigned* __restrict__ counts, int N) {
  constexpr int RPT = VOX / 4;
  int t = blockIdx.x * 256 + threadIdx.x;

  if (t < P * RPT) {
    int p = t / RPT;
    int r4 = (t - p * RPT) * 4;
    const float* src = g + (size_t)p * C * VOX + r4;
    float4 v[C];
#pragma unroll
    for (int c = 0; c < C; ++c)
      v[c] = *reinterpret_cast<const float4*>(src + (size_t)c * VOX);
    union { __half h[48]; uint4 u[6]; } pk;
#pragma unroll
    for (int j = 0; j < 4; ++j) {
#pragma unroll
      for (int c = 0; c < C; ++c) {
        float f = (j == 0) ? v[c].x : (j == 1) ? v[c].y : (j == 2) ? v[c].z : v[c].w;
        pk.h[j * C + c] = __float2half_rn(f);
      }
    }
    uint4* dst = reinterpret_cast<uint4*>(gt + ((size_t)p * VOX + r4) * C);
#pragma unroll
    for (int k = 0; k < 6; ++k) dst[k] = pk.u[k];
  }

  if (t < N) {
    float u[3];
    norm_u(xyz, t, mn, mx, u);
    atomicAdd(&counts[cell_of_u(u)], 1u);
  }
}

// Single-block exclusive scan of CELLS (=32768) counters.
__global__ __launch_bounds__(1024) void scan_kernel(
    const unsigned* __restrict__ counts, unsigned* __restrict__ offsets) {
  __shared__ unsigned part[1024];
  int t = threadIdx.x;
  unsigned base = t * (CELLS / 1024);
  unsigned local[CELLS / 1024];
  unsigned s = 0;
#pragma unroll
  for (int i = 0; i < CELLS / 1024; ++i) { local[i] = s; s += counts[base + i]; }
  part[t] = s;
  __syncthreads();
  for (int off = 1; off < 1024; off <<= 1) {
    unsigned v = (t >= off) ? part[t - off] : 0u;
    __syncthreads();
    part[t] += v;
    __syncthreads();
  }
  unsigned prev = (t == 0) ? 0u : part[t - 1];
#pragma unroll
  for (int i = 0; i < CELLS / 1024; ++i) offsets[base + i] = prev + local[i];
}

// Scatter normalized points into cell-sorted order: rec = {ux,uy,uz,idx}.
__global__ __launch_bounds__(256) void scatter_kernel(
    const float* __restrict__ xyz, const float* __restrict__ mn,
    const float* __restrict__ mx, unsigned* __restrict__ offsets,
    float4* __restrict__ sorted, int N) {
  int n = blockIdx.x * 256 + threadIdx.x;
  if (n >= N) return;
  float u[3];
  norm_u(xyz, n, mn, mx, u);
  unsigned slot = atomicAdd(&offsets[cell_of_u(u)], 1u);
  float4 rec;
  rec.x = u[0]; rec.y = u[1]; rec.z = u[2];
  rec.w = __uint_as_float((unsigned)n);
  sorted[slot] = rec;
}

// ---------------------------------------------------------------------------
// Sample kernel restructured to fit <=64 VGPR NATURALLY (no forced bounds):
//  - 32-bit byte offsets off uniform base (saddr + voffset addressing)
//  - rolling 3-region issue: peak 9 quads (36 data VGPRs) in flight
//  - running pbase byte offset; weights held as 6 scalars
// If the allocator lands <=64, residency doubles (8 waves/EU).
// ---------------------------------------------------------------------------
__global__ __launch_bounds__(256) void sample_sorted_kernel(
    const float4* __restrict__ pts, const __half* __restrict__ g,
    float* __restrict__ out, int N) {
  // XCD-bijective chunked block swizzle (sorted order -> per-XCD L2 chunks).
  unsigned nwg = gridDim.x, bid = blockIdx.x;
  unsigned q = nwg / 8u, r = nwg % 8u;
  unsigned xcd = bid % 8u, j = bid / 8u;
  unsigned swz = (xcd < r ? xcd * (q + 1u) : r * (q + 1u) + (xcd - r) * q) + j;
  int n = (int)(swz * 256u + threadIdx.x);
  if (n >= N) return;

  float4 rec = pts[n];

  float acc[C];
#pragma unroll
  for (int c = 0; c < C; ++c) acc[c] = 0.0f;

  const char* gb = reinterpret_cast<const char*>(g);
  unsigned pbase = 0u;                      // byte base of current p-slice

  auto gather = [&](float ex, float ey, float ez) {
    // (e+1)*47.5 mapping; inputs are in [-1,1] so t in [0,95].
    float tz = fmaf(ez, 47.5f, 47.5f);
    float ty = fmaf(ey, 47.5f, 47.5f);
    float tx = fmaf(ex, 47.5f, 47.5f);
    float fz = floorf(tz), fy = floorf(ty), fx = floorf(tx);
    int z0 = (int)fz, y0 = (int)fy, x0 = (int)fx;
    int y1 = y0 + 1 > D - 1 ? D - 1 : y0 + 1;
    int x1 = x0 + 1 > D - 1 ? D - 1 : x0 + 1;
    float wz1 = tz - fz, wz0 = 1.0f - wz1;
    float wy1 = ty - fy, wy0 = 1.0f - wy1;
    float wx1 = tx - fx, wx0 = 1.0f - wx1;

    auto consume = [&](const uint4& q0, const uint4& q1, const uint4& q2,
                       float wxy) {
      float w0 = wxy * wz0, w1 = wxy * wz1;
      auto acc2 = [&](unsigned lo, unsigned hi, int c) {
        __half2 hl = *reinterpret_cast<const __half2*>(&lo);
        __half2 hh = *reinterpret_cast<const __half2*>(&hi);
        float2 f0 = __half22float2(hl);
        float2 f1 = __half22float2(hh);
        acc[c]     = fmaf(w0, f0.x, fmaf(w1, f1.x, acc[c]));
        acc[c + 1] = fmaf(w0, f0.y, fmaf(w1, f1.y, acc[c + 1]));
      };
      acc2(q0.x, q1.z, 0);
      acc2(q0.y, q1.w, 2);
      acc2(q0.z, q2.x, 4);
      acc2(q0.w, q2.y, 6);
      acc2(q1.x, q2.z, 8);
      acc2(q1.y, q2.w, 10);
    };

    // Byte offsets (fp16 grid is 233 MB < 4 GB -> 32-bit).
    unsigned bx0 = (unsigned)(x0 * (D * D) + z0);
    unsigned bx1 = (unsigned)(x1 * (D * D) + z0);
    unsigned by0 = (unsigned)(y0 * D), by1 = (unsigned)(y1 * D);

    // Rolling 3-region issue. z0==95 overreads 24B at weight 0 (in-allocation).
    unsigned o00 = pbase + (bx0 + by0) * 24u;
    unsigned o01 = pbase + (bx0 + by1) * 24u;
    unsigned o10 = pbase + (bx1 + by0) * 24u;
    uint4 a0 = *reinterpret_cast<const uint4*>(gb + o00);
    uint4 a1 = *reinterpret_cast<const uint4*>(gb + o00 + 16);
    uint4 a2 = *reinterpret_cast<const uint4*>(gb + o00 + 32);
    uint4 b0 = *reinterpret_cast<const uint4*>(gb + o01);
    uint4 b1 = *reinterpret_cast<const uint4*>(gb + o01 + 16);
    uint4 b2 = *reinterpret_cast<const uint4*>(gb + o01 + 32);
    uint4 c0 = *reinterpret_cast<const uint4*>(gb + o10);
    uint4 c1 = *reinterpret_cast<const uint4*>(gb + o10 + 16);
    uint4 c2 = *reinterpret_cast<const uint4*>(gb + o10 + 32);

    consume(a0, a1, a2, wx0 * wy0);

    unsigned o11 = pbase + (bx1 + by1) * 24u;
    uint4 d0 = *reinterpret_cast<const uint4*>(gb + o11);
    uint4 d1 = *reinterpret_cast<const uint4*>(gb + o11 + 16);
    uint4 d2 = *reinterpret_cast<const uint4*>(gb + o11 + 32);

    consume(b0, b1, b2, wx0 * wy1);
    consume(c0, c1, c2, wx1 * wy0);
    consume(d0, d1, d2, wx1 * wy1);

    pbase += (unsigned)VOX * 24u;           // advance one p-slice
  };

  gather(rec.x, rec.y, rec.z);              // p=0 identity

  float s0 = sinf(rec.x), c0_ = cosf(rec.x);
  float s1 = sinf(rec.y), c1_ = cosf(rec.y);
  float s2 = sinf(rec.z), c2_ = cosf(rec.z);
  for (int f = 0; f < 5; ++f) {             // f = 1,2,4,8,16
    gather(s0, s1, s2);
    gather(c0_, c1_, c2_);
    if (f < 4) {
      float ns;
      ns = 2.0f * s0 * c0_; c0_ = 1.0f - 2.0f * s0 * s0; s0 = ns;
      ns = 2.0f * s1 * c1_; c1_ = 1.0f - 2.0f * s1 * s1; s1 = ns;
      ns = 2.0f * s2 * c2_; c2_ = 1.0f - 2.0f * s2 * s2; s2 = ns;
    }
  }

  constexpr float inv = 1.0f / (float)P;
  float4 r0, r1, r2;
  r0.x = acc[0] * inv;  r0.y = acc[1] * inv;  r0.z = acc[2] * inv;  r0.w = acc[3] * inv;
  r1.x = acc[4] * inv;  r1.y = acc[5] * inv;  r1.z = acc[6] * inv;  r1.w = acc[7] * inv;
  r2.x = acc[8] * inv;  r2.y = acc[9] * inv;  r2.z = acc[10] * inv; r2.w = acc[11] * inv;
  unsigned oidx = __float_as_uint(rec.w);
  float4* o4 = reinterpret_cast<float4*>(out + (size_t)oidx * C);
  o4[0] = r0; o4[1] = r1; o4[2] = r2;
}

// ---------------------------------------------------------------------------
// Fallback: unsorted fp16 path.
// ---------------------------------------------------------------------------
__global__ __launch_bounds__(256) void sample_fp16_kernel(
    const float* __restrict__ xyz, const __half* __restrict__ g,
    const float* __restrict__ xyz_min, const float* __restrict__ xyz_max,
    float* __restrict__ out, int N) {
  int n = blockIdx.x * 256 + threadIdx.x;
  if (n >= N) return;
  float u[3];
#pragma unroll
  for (int d = 0; d < 3; ++d) {
    float mn = xyz_min[d], mx = xyz_max[d];
    u[d] = (xyz[3 * (size_t)n + d] - mn) * (2.0f / (mx - mn)) - 1.0f;
  }
  float acc[C];
#pragma unroll
  for (int c = 0; c < C; ++c) acc[c] = 0.0f;
  const ushort* gu = reinterpret_cast<const ushort*>(g);
  int p = 0;
  auto gather = [&](float ex, float ey, float ez) {
    float tz = (ez + 1.0f) * (0.5f * (D - 1));
    float ty = (ey + 1.0f) * (0.5f * (D - 1));
    float tx = (ex + 1.0f) * (0.5f * (D - 1));
    int z0 = (int)floorf(tz); z0 = z0 < 0 ? 0 : (z0 > D - 1 ? D - 1 : z0);
    int y0 = (int)floorf(ty); y0 = y0 < 0 ? 0 : (y0 > D - 1 ? D - 1 : y0);
    int x0 = (int)floorf(tx); x0 = x0 < 0 ? 0 : (x0 > D - 1 ? D - 1 : x0);
    int y1 = y0 + 1 > D - 1 ? D - 1 : y0 + 1;
    int x1 = x0 + 1 > D - 1 ? D - 1 : x0 + 1;
    float wz = tz - (float)z0, wy = ty - (float)y0, wx = tx - (float)x0;
    float wz0 = 1.0f - wz, wz1 = wz;
    float wy0 = 1.0f - wy, wy1 = wy;
    float wx0 = 1.0f - wx, wx1 = wx;
    size_t pbase = (size_t)p * VOX;
    const uint4* r00 = reinterpret_cast<const uint4*>(gu + (pbase + (size_t)((x0 * D + y0) * D + z0)) * C);
    const uint4* r01 = reinterpret_cast<const uint4*>(gu + (pbase + (size_t)((x0 * D + y1) * D + z0)) * C);
    const uint4* r10 = reinterpret_cast<const uint4*>(gu + (pbase + (size_t)((x1 * D + y0) * D + z0)) * C);
    const uint4* r11 = reinterpret_cast<const uint4*>(gu + (pbase + (size_t)((x1 * D + y1) * D + z0)) * C);
    uint4 a0 = r00[0], a1 = r00[1], a2 = r00[2];
    uint4 b0 = r01[0], b1 = r01[1], b2 = r01[2];
    uint4 c0 = r10[0], c1 = r10[1], c2 = r10[2];
    uint4 d0 = r11[0], d1 = r11[1], d2 = r11[2];
    auto acc2 = [&](unsigned lo, unsigned hi, float w0, float w1, int c) {
      __half2 hl = *reinterpret_cast<const __half2*>(&lo);
      __half2 hh = *reinterpret_cast<const __half2*>(&hi);
      float2 f0 = __half22float2(hl);
      float2 f1 = __half22float2(hh);
      acc[c]     = fmaf(w0, f0.x, fmaf(w1, f1.x, acc[c]));
      acc[c + 1] = fmaf(w0, f0.y, fmaf(w1, f1.y, acc[c + 1]));
    };
    auto region = [&](const uint4& q0, const uint4& q1, const uint4& q2, float wxy) {
      float w0 = wxy * wz0, w1 = wxy * wz1;
      acc2(q0.x, q1.z, w0, w1, 0);
      acc2(q0.y, q1.w, w0, w1, 2);
      acc2(q0.z, q2.x, w0, w1, 4);
      acc2(q0.w, q2.y, w0, w1, 6);
      acc2(q1.x, q2.z, w0, w1, 8);
      acc2(q1.y, q2.w, w0, w1, 10);
    };
    region(a0, a1, a2, wx0 * wy0);
    region(b0, b1, b2, wx0 * wy1);
    region(c0, c1, c2, wx1 * wy0);
    region(d0, d1, d2, wx1 * wy1);
    ++p;
  };
  gather(u[0], u[1], u[2]);
  float s[3], co[3];
#pragma unroll
  for (int d = 0; d < 3; ++d) { s[d] = sinf(u[d]); co[d] = cosf(u[d]); }
  for (int f = 0; f < 5; ++f) {
    gather(s[0], s[1], s[2]);
    gather(co[0], co[1], co[2]);
    if (f < 4) {
#pragma unroll
      for (int d = 0; d < 3; ++d) {
        float ns = 2.0f * s[d] * co[d];
        float nc = 1.0f - 2.0f * s[d] * s[d];
        s[d] = ns; co[d] = nc;
      }
    }
  }
  constexpr float inv = 1.0f / (float)P;
  float4 r0, r1, r2;
  r0.x = acc[0] * inv;  r0.y = acc[1] * inv;  r0.z = acc[2] * inv;  r0.w = acc[3] * inv;
  r1.x = acc[4] * inv;  r1.y = acc[5] * inv;  r1.z = acc[6] * inv;  r1.w = acc[7] * inv;
  r2.x = acc[8] * inv;  r2.y = acc[9] * inv;  r2.z = acc[10] * inv; r2.w = acc[11] * inv;
  float4* o4 = reinterpret_cast<float4*>(out + (size_t)n * C);
  o4[0] = r0; o4[1] = r1; o4[2] = r2;
}

// Last-resort naive fp32 path.
__global__ __launch_bounds__(256) void sample_naive_kernel(
    const float* __restrict__ xyz, const float* __restrict__ g,
    const float* __restrict__ xyz_min, const float* __restrict__ xyz_max,
    float* __restrict__ out, int N) {
  int n = blockIdx.x * 256 + threadIdx.x;
  if (n >= N) return;
  float u[3];
#pragma unroll
  for (int d = 0; d < 3; ++d) {
    float mn = xyz_min[d], mx = xyz_max[d];
    u[d] = (xyz[3 * (size_t)n + d] - mn) * (2.0f / (mx - mn)) - 1.0f;
  }
  float acc[C];
#pragma unroll
  for (int c = 0; c < C; ++c) acc[c] = 0.0f;
  int p = 0;
  auto gather = [&](float ex, float ey, float ez) {
    float e[3] = {ez, ey, ex};
    int i0[3], i1[3]; float w[3];
#pragma unroll
    for (int d = 0; d < 3; ++d) {
      float t = (e[d] + 1.0f) * (0.5f * (D - 1));
      int a = (int)floorf(t);
      a = a < 0 ? 0 : (a > D - 1 ? D - 1 : a);
      int b = a + 1 > D - 1 ? D - 1 : a + 1;
      i0[d] = a; i1[d] = b; w[d] = t - (float)a;
    }
    const float* gp = g + (size_t)p * C * VOX;
    auto corner = [&](int iz, int iy, int ix, float wgt) {
      int o = (ix * D + iy) * D + iz;
#pragma unroll
      for (int c = 0; c < C; ++c) acc[c] += wgt * gp[(size_t)c * VOX + o];
    };
    corner(i0[0], i0[1], i0[2], (1 - w[0]) * (1 - w[1]) * (1 - w[2]));
    corner(i1[0], i0[1], i0[2], w[0] * (1 - w[1]) * (1 - w[2]));
    corner(i0[0], i1[1], i0[2], (1 - w[0]) * w[1] * (1 - w[2]));
    corner(i1[0], i1[1], i0[2], w[0] * w[1] * (1 - w[2]));
    corner(i0[0], i0[1], i1[2], (1 - w[0]) * (1 - w[1]) * w[2]);
    corner(i1[0], i0[1], i1[2], w[0] * (1 - w[1]) * w[2]);
    corner(i0[0], i1[1], i1[2], (1 - w[0]) * w[1] * w[2]);
    corner(i1[0], i1[1], i1[2], w[0] * w[1] * w[2]);
    ++p;
  };
  gather(u[0], u[1], u[2]);
  float s[3], co[3];
#pragma unroll
  for (int d = 0; d < 3; ++d) { s[d] = sinf(u[d]); co[d] = cosf(u[d]); }
  for (int f = 0; f < 5; ++f) {
    gather(s[0], s[1], s[2]);
    gather(co[0], co[1], co[2]);
    if (f < 4) {
#pragma unroll
      for (int d = 0; d < 3; ++d) {
        float ns = 2.0f * s[d] * co[d];
        float nc = 1.0f - 2.0f * s[d] * s[d];
        s[d] = ns; co[d] = nc;
      }
    }
  }
  constexpr float inv = 1.0f / (float)P;
#pragma unroll
  for (int c = 0; c < C; ++c) out[(size_t)n * C + c] = acc[c] * inv;
}

extern "C" void kernel_launch(void* const* d_in, const int* in_sizes, int n_in,
                              void* d_out, int out_size, void* d_ws, size_t ws_size,
                              hipStream_t stream) {
  const float* xyz = (const float*)d_in[0];
  const float* grid = (const float*)d_in[1];
  const float* mn = (const float*)d_in[2];
  const float* mx = (const float*)d_in[3];
  float* out = (float*)d_out;
  int N = in_sizes[0] / 3;

  size_t gt_bytes = (size_t)P * VOX * C * sizeof(__half);   // ~233.6 MB
  size_t sorted_bytes = (size_t)N * sizeof(float4);         // 12.8 MB
  size_t cnt_bytes = (size_t)CELLS * sizeof(unsigned);      // 128 KB

  size_t need_sorted = sorted_bytes + gt_bytes + 2 * cnt_bytes + 1024;
  size_t need_min = gt_bytes + 256;

  int sblocks = (N + 255) / 256;
  int tblocks = (P * (VOX / 4) + 255) / 256;   // covers N too (2.43M > 800k)

  if (ws_size >= need_sorted) {
    char* w = (char*)d_ws;
    float4*   sorted  = (float4*)w;   w += sorted_bytes;
    __half*   gt      = (__half*)w;   w += gt_bytes;
    unsigned* counts  = (unsigned*)w; w += cnt_bytes;
    unsigned* offsets = (unsigned*)w;

    hipMemsetAsync(counts, 0, cnt_bytes, stream);
    transpose_count_kernel<<<tblocks, 256, 0, stream>>>(grid, gt, xyz, mn, mx,
                                                        counts, N);
    scan_kernel<<<1, 1024, 0, stream>>>(counts, offsets);
    scatter_kernel<<<sblocks, 256, 0, stream>>>(xyz, mn, mx, offsets, sorted, N);
    sample_sorted_kernel<<<sblocks, 256, 0, stream>>>(sorted, gt, out, N);
  } else if (ws_size >= need_min) {
    __half* gt = (__half*)d_ws;
    transpose_count_kernel<<<tblocks, 256, 0, stream>>>(grid, gt, xyz, mn, mx,
                                                        nullptr, 0);
    sample_fp16_kernel<<<sblocks, 256, 0, stream>>>(xyz, gt, mn, mx, out, N);
  } else {
    sample_naive_kernel<<<sblocks, 256, 0, stream>>>(xyz, grid, mn, mx, out, N);
  }
}

// Round 10
// 567.366 us; speedup vs baseline: 2.3636x; 1.0063x over previous
//
#include <hip/hip_runtime.h>
#include <hip/hip_fp16.h>
#include <cmath>

constexpr int D   = 96;
constexpr int C   = 12;
constexpr int P   = 11;   // 1 + 2*5
constexpr int VOX = D * D * D;        // 884736
constexpr int CELLS = 32 * 32 * 32;   // Morton 32^3 sort buckets

// ---------------------------------------------------------------------------
// Morton cell key
// ---------------------------------------------------------------------------
__device__ __forceinline__ unsigned spread5(unsigned v) {
  v &= 31u;
  v = (v | (v << 8)) & 0x100Fu;
  v = (v | (v << 4)) & 0x10C3u;
  v = (v | (v << 2)) & 0x1249u;
  return v;
}

__device__ __forceinline__ unsigned cell_of_u(const float u[3]) {
  unsigned cc[3];
#pragma unroll
  for (int d = 0; d < 3; ++d) {
    int c = (int)((u[d] + 1.0f) * 16.0f);
    c = c < 0 ? 0 : (c > 31 ? 31 : c);
    cc[d] = (unsigned)c;
  }
  return spread5(cc[0]) | (spread5(cc[1]) << 1) | (spread5(cc[2]) << 2);
}

__device__ __forceinline__ void norm_u(const float* __restrict__ xyz, int n,
                                       const float* __restrict__ mn,
                                       const float* __restrict__ mx, float u[3]) {
#pragma unroll
  for (int d = 0; d < 3; ++d)
    u[d] = (xyz[3 * (size_t)n + d] - mn[d]) * (2.0f / (mx[d] - mn[d])) - 1.0f;
}

// ---------------------------------------------------------------------------
// Transpose+downconvert [P*C][x][y][z] f32 -> [P][x][y][z][C] fp16, with the
// histogram count fused in (threads t < N also bin their point).
// ---------------------------------------------------------------------------
__global__ __launch_bounds__(256) void transpose_count_kernel(
    const float* __restrict__ g, __half* __restrict__ gt,
    const float* __restrict__ xyz, const float* __restrict__ mn,
    const float* __restrict__ mx, unsigned* __restrict__ counts, int N) {
  constexpr int RPT = VOX / 4;
  int t = blockIdx.x * 256 + threadIdx.x;

  if (t < P * RPT) {
    int p = t / RPT;
    int r4 = (t - p * RPT) * 4;
    const float* src = g + (size_t)p * C * VOX + r4;
    float4 v[C];
#pragma unroll
    for (int c = 0; c < C; ++c)
      v[c] = *reinterpret_cast<const float4*>(src + (size_t)c * VOX);
    union { __half h[48]; uint4 u[6]; } pk;
#pragma unroll
    for (int j = 0; j < 4; ++j) {
#pragma unroll
      for (int c = 0; c < C; ++c) {
        float f = (j == 0) ? v[c].x : (j == 1) ? v[c].y : (j == 2) ? v[c].z : v[c].w;
        pk.h[j * C + c] = __float2half_rn(f);
      }
    }
    uint4* dst = reinterpret_cast<uint4*>(gt + ((size_t)p * VOX + r4) * C);
#pragma unroll
    for (int k = 0; k < 6; ++k) dst[k] = pk.u[k];
  }

  if (t < N) {
    float u[3];
    norm_u(xyz, t, mn, mx, u);
    atomicAdd(&counts[cell_of_u(u)], 1u);
  }
}

// Single-block exclusive scan of CELLS (=32768) counters.
__global__ __launch_bounds__(1024) void scan_kernel(
    const unsigned* __restrict__ counts, unsigned* __restrict__ offsets) {
  __shared__ unsigned part[1024];
  int t = threadIdx.x;
  unsigned base = t * (CELLS / 1024);
  unsigned local[CELLS / 1024];
  unsigned s = 0;
#pragma unroll
  for (int i = 0; i < CELLS / 1024; ++i) { local[i] = s; s += counts[base + i]; }
  part[t] = s;
  __syncthreads();
  for (int off = 1; off < 1024; off <<= 1) {
    unsigned v = (t >= off) ? part[t - off] : 0u;
    __syncthreads();
    part[t] += v;
    __syncthreads();
  }
  unsigned prev = (t == 0) ? 0u : part[t - 1];
#pragma unroll
  for (int i = 0; i < CELLS / 1024; ++i) offsets[base + i] = prev + local[i];
}

// Scatter normalized points into cell-sorted order: rec = {ux,uy,uz,idx}.
__global__ __launch_bounds__(256) void scatter_kernel(
    const float* __restrict__ xyz, const float* __restrict__ mn,
    const float* __restrict__ mx, unsigned* __restrict__ offsets,
    float4* __restrict__ sorted, int N) {
  int n = blockIdx.x * 256 + threadIdx.x;
  if (n >= N) return;
  float u[3];
  norm_u(xyz, n, mn, mx, u);
  unsigned slot = atomicAdd(&offsets[cell_of_u(u)], 1u);
  float4 rec;
  rec.x = u[0]; rec.y = u[1]; rec.z = u[2];
  rec.w = __uint_as_float((unsigned)n);
  sorted[slot] = rec;
}

// ---------------------------------------------------------------------------
// Sample kernel: 2-region rolling window sized to fit <=64 VGPR naturally.
// Peak live set ~= 12 acc + 6 in-flight quads (24) + sincos(6) + weights(6)
// + addr(5) + misc(8) ~= 61 regs -> 8 waves/EU if the allocator cooperates.
// ---------------------------------------------------------------------------
__global__ __launch_bounds__(256) void sample_sorted_kernel(
    const float4* __restrict__ pts, const __half* __restrict__ g,
    float* __restrict__ out, int N) {
  // XCD-bijective chunked block swizzle (sorted order -> per-XCD L2 chunks).
  unsigned nwg = gridDim.x, bid = blockIdx.x;
  unsigned q = nwg / 8u, r = nwg % 8u;
  unsigned xcd = bid % 8u, j = bid / 8u;
  unsigned swz = (xcd < r ? xcd * (q + 1u) : r * (q + 1u) + (xcd - r) * q) + j;
  int n = (int)(swz * 256u + threadIdx.x);
  if (n >= N) return;

  float4 rec = pts[n];

  float acc[C];
#pragma unroll
  for (int c = 0; c < C; ++c) acc[c] = 0.0f;

  const char* gb = reinterpret_cast<const char*>(g);
  unsigned pbase = 0u;                      // byte base of current p-slice

  auto gather = [&](float ex, float ey, float ez) {
    float tz = fmaf(ez, 47.5f, 47.5f);
    float ty = fmaf(ey, 47.5f, 47.5f);
    float tx = fmaf(ex, 47.5f, 47.5f);
    float fz = floorf(tz), fy = floorf(ty), fx = floorf(tx);
    int z0 = (int)fz, y0 = (int)fy, x0 = (int)fx;
    int y1 = y0 + 1 > D - 1 ? D - 1 : y0 + 1;
    int x1 = x0 + 1 > D - 1 ? D - 1 : x0 + 1;
    float wz1 = tz - fz, wz0 = 1.0f - wz1;
    float wy1 = ty - fy, wy0 = 1.0f - wy1;
    float wx1 = tx - fx, wx0 = 1.0f - wx1;

    auto consume = [&](const uint4& q0, const uint4& q1, const uint4& q2,
                       float wxy) {
      float w0 = wxy * wz0, w1 = wxy * wz1;
      auto acc2 = [&](unsigned lo, unsigned hi, int c) {
        __half2 hl = *reinterpret_cast<const __half2*>(&lo);
        __half2 hh = *reinterpret_cast<const __half2*>(&hi);
        float2 f0 = __half22float2(hl);
        float2 f1 = __half22float2(hh);
        acc[c]     = fmaf(w0, f0.x, fmaf(w1, f1.x, acc[c]));
        acc[c + 1] = fmaf(w0, f0.y, fmaf(w1, f1.y, acc[c + 1]));
      };
      acc2(q0.x, q1.z, 0);
      acc2(q0.y, q1.w, 2);
      acc2(q0.z, q2.x, 4);
      acc2(q0.w, q2.y, 6);
      acc2(q1.x, q2.z, 8);
      acc2(q1.y, q2.w, 10);
    };

    unsigned bx0 = (unsigned)(x0 * (D * D) + z0);
    unsigned bx1 = (unsigned)(x1 * (D * D) + z0);
    unsigned by0 = (unsigned)(y0 * D), by1 = (unsigned)(y1 * D);

    // 2-region rolling window (z0==95 overread is weight-0, in-allocation).
    unsigned o = pbase + (bx0 + by0) * 24u;
    uint4 a0 = *reinterpret_cast<const uint4*>(gb + o);
    uint4 a1 = *reinterpret_cast<const uint4*>(gb + o + 16);
    uint4 a2 = *reinterpret_cast<const uint4*>(gb + o + 32);
    o = pbase + (bx0 + by1) * 24u;
    uint4 b0 = *reinterpret_cast<const uint4*>(gb + o);
    uint4 b1 = *reinterpret_cast<const uint4*>(gb + o + 16);
    uint4 b2 = *reinterpret_cast<const uint4*>(gb + o + 32);

    consume(a0, a1, a2, wx0 * wy0);

    o = pbase + (bx1 + by0) * 24u;
    a0 = *reinterpret_cast<const uint4*>(gb + o);
    a1 = *reinterpret_cast<const uint4*>(gb + o + 16);
    a2 = *reinterpret_cast<const uint4*>(gb + o + 32);

    consume(b0, b1, b2, wx0 * wy1);

    o = pbase + (bx1 + by1) * 24u;
    b0 = *reinterpret_cast<const uint4*>(gb + o);
    b1 = *reinterpret_cast<const uint4*>(gb + o + 16);
    b2 = *reinterpret_cast<const uint4*>(gb + o + 32);

    consume(a0, a1, a2, wx1 * wy0);
    consume(b0, b1, b2, wx1 * wy1);

    pbase += (unsigned)VOX * 24u;           // advance one p-slice
  };

  gather(rec.x, rec.y, rec.z);              // p=0 identity

  float s0 = sinf(rec.x), c0_ = cosf(rec.x);
  float s1 = sinf(rec.y), c1_ = cosf(rec.y);
  float s2 = sinf(rec.z), c2_ = cosf(rec.z);
  for (int f = 0; f < 5; ++f) {             // f = 1,2,4,8,16
    gather(s0, s1, s2);
    gather(c0_, c1_, c2_);
    if (f < 4) {
      float ns;
      ns = 2.0f * s0 * c0_; c0_ = 1.0f - 2.0f * s0 * s0; s0 = ns;
      ns = 2.0f * s1 * c1_; c1_ = 1.0f - 2.0f * s1 * s1; s1 = ns;
      ns = 2.0f * s2 * c2_; c2_ = 1.0f - 2.0f * s2 * s2; s2 = ns;
    }
  }

  constexpr float inv = 1.0f / (float)P;
  float4 r0, r1, r2;
  r0.x = acc[0] * inv;  r0.y = acc[1] * inv;  r0.z = acc[2] * inv;  r0.w = acc[3] * inv;
  r1.x = acc[4] * inv;  r1.y = acc[5] * inv;  r1.z = acc[6] * inv;  r1.w = acc[7] * inv;
  r2.x = acc[8] * inv;  r2.y = acc[9] * inv;  r2.z = acc[10] * inv; r2.w = acc[11] * inv;
  unsigned oidx = __float_as_uint(rec.w);
  float4* o4 = reinterpret_cast<float4*>(out + (size_t)oidx * C);
  o4[0] = r0; o4[1] = r1; o4[2] = r2;
}

// ---------------------------------------------------------------------------
// Fallback: unsorted fp16 path.
// ---------------------------------------------------------------------------
__global__ __launch_bounds__(256) void sample_fp16_kernel(
    const float* __restrict__ xyz, const __half* __restrict__ g,
    const float* __restrict__ xyz_min, const float* __restrict__ xyz_max,
    float* __restrict__ out, int N) {
  int n = blockIdx.x * 256 + threadIdx.x;
  if (n >= N) return;
  float u[3];
#pragma unroll
  for (int d = 0; d < 3; ++d) {
    float mn = xyz_min[d], mx = xyz_max[d];
    u[d] = (xyz[3 * (size_t)n + d] - mn) * (2.0f / (mx - mn)) - 1.0f;
  }
  float acc[C];
#pragma unroll
  for (int c = 0; c < C; ++c) acc[c] = 0.0f;
  const ushort* gu = reinterpret_cast<const ushort*>(g);
  int p = 0;
  auto gather = [&](float ex, float ey, float ez) {
    float tz = (ez + 1.0f) * (0.5f * (D - 1));
    float ty = (ey + 1.0f) * (0.5f * (D - 1));
    float tx = (ex + 1.0f) * (0.5f * (D - 1));
    int z0 = (int)floorf(tz); z0 = z0 < 0 ? 0 : (z0 > D - 1 ? D - 1 : z0);
    int y0 = (int)floorf(ty); y0 = y0 < 0 ? 0 : (y0 > D - 1 ? D - 1 : y0);
    int x0 = (int)floorf(tx); x0 = x0 < 0 ? 0 : (x0 > D - 1 ? D - 1 : x0);
    int y1 = y0 + 1 > D - 1 ? D - 1 : y0 + 1;
    int x1 = x0 + 1 > D - 1 ? D - 1 : x0 + 1;
    float wz = tz - (float)z0, wy = ty - (float)y0, wx = tx - (float)x0;
    float wz0 = 1.0f - wz, wz1 = wz;
    float wy0 = 1.0f - wy, wy1 = wy;
    float wx0 = 1.0f - wx, wx1 = wx;
    size_t pbase = (size_t)p * VOX;
    const uint4* r00 = reinterpret_cast<const uint4*>(gu + (pbase + (size_t)((x0 * D + y0) * D + z0)) * C);
    const uint4* r01 = reinterpret_cast<const uint4*>(gu + (pbase + (size_t)((x0 * D + y1) * D + z0)) * C);
    const uint4* r10 = reinterpret_cast<const uint4*>(gu + (pbase + (size_t)((x1 * D + y0) * D + z0)) * C);
    const uint4* r11 = reinterpret_cast<const uint4*>(gu + (pbase + (size_t)((x1 * D + y1) * D + z0)) * C);
    uint4 a0 = r00[0], a1 = r00[1], a2 = r00[2];
    uint4 b0 = r01[0], b1 = r01[1], b2 = r01[2];
    uint4 c0 = r10[0], c1 = r10[1], c2 = r10[2];
    uint4 d0 = r11[0], d1 = r11[1], d2 = r11[2];
    auto acc2 = [&](unsigned lo, unsigned hi, float w0, float w1, int c) {
      __half2 hl = *reinterpret_cast<const __half2*>(&lo);
      __half2 hh = *reinterpret_cast<const __half2*>(&hi);
      float2 f0 = __half22float2(hl);
      float2 f1 = __half22float2(hh);
      acc[c]     = fmaf(w0, f0.x, fmaf(w1, f1.x, acc[c]));
      acc[c + 1] = fmaf(w0, f0.y, fmaf(w1, f1.y, acc[c + 1]));
    };
    auto region = [&](const uint4& q0, const uint4& q1, const uint4& q2, float wxy) {
      float w0 = wxy * wz0, w1 = wxy * wz1;
      acc2(q0.x, q1.z, w0, w1, 0);
      acc2(q0.y, q1.w, w0, w1, 2);
      acc2(q0.z, q2.x, w0, w1, 4);
      acc2(q0.w, q2.y, w0, w1, 6);
      acc2(q1.x, q2.z, w0, w1, 8);
      acc2(q1.y, q2.w, w0, w1, 10);
    };
    region(a0, a1, a2, wx0 * wy0);
    region(b0, b1, b2, wx0 * wy1);
    region(c0, c1, c2, wx1 * wy0);
    region(d0, d1, d2, wx1 * wy1);
    ++p;
  };
  gather(u[0], u[1], u[2]);
  float s[3], co[3];
#pragma unroll
  for (int d = 0; d < 3; ++d) { s[d] = sinf(u[d]); co[d] = cosf(u[d]); }
  for (int f = 0; f < 5; ++f) {
    gather(s[0], s[1], s[2]);
    gather(co[0], co[1], co[2]);
    if (f < 4) {
#pragma unroll
      for (int d = 0; d < 3; ++d) {
        float ns = 2.0f * s[d] * co[d];
        float nc = 1.0f - 2.0f * s[d] * s[d];
        s[d] = ns; co[d] = nc;
      }
    }
  }
  constexpr float inv = 1.0f / (float)P;
  float4 r0, r1, r2;
  r0.x = acc[0] * inv;  r0.y = acc[1] * inv;  r0.z = acc[2] * inv;  r0.w = acc[3] * inv;
  r1.x = acc[4] * inv;  r1.y = acc[5] * inv;  r1.z = acc[6] * inv;  r1.w = acc[7] * inv;
  r2.x = acc[8] * inv;  r2.y = acc[9] * inv;  r2.z = acc[10] * inv; r2.w = acc[11] * inv;
  float4* o4 = reinterpret_cast<float4*>(out + (size_t)n * C);
  o4[0] = r0; o4[1] = r1; o4[2] = r2;
}

// Last-resort naive fp32 path.
__global__ __launch_bounds__(256) void sample_naive_kernel(
    const float* __restrict__ xyz, const float* __restrict__ g,
    const float* __restrict__ xyz_min, const float* __restrict__ xyz_max,
    float* __restrict__ out, int N) {
  int n = blockIdx.x * 256 + threadIdx.x;
  if (n >= N) return;
  float u[3];
#pragma unroll
  for (int d = 0; d < 3; ++d) {
    float mn = xyz_min[d], mx = xyz_max[d];
    u[d] = (xyz[3 * (size_t)n + d] - mn) * (2.0f / (mx - mn)) - 1.0f;
  }
  float acc[C];
#pragma unroll
  for (int c = 0; c < C; ++c) acc[c] = 0.0f;
  int p = 0;
  auto gather = [&](float ex, float ey, float ez) {
    float e[3] = {ez, ey, ex};
    int i0[3], i1[3]; float w[3];
#pragma unroll
    for (int d = 0; d < 3; ++d) {
      float t = (e[d] + 1.0f) * (0.5f * (D - 1));
      int a = (int)floorf(t);
      a = a < 0 ? 0 : (a > D - 1 ? D - 1 : a);
      int b = a + 1 > D - 1 ? D - 1 : a + 1;
      i0[d] = a; i1[d] = b; w[d] = t - (float)a;
    }
    const float* gp = g + (size_t)p * C * VOX;
    auto corner = [&](int iz, int iy, int ix, float wgt) {
      int o = (ix * D + iy) * D + iz;
#pragma unroll
      for (int c = 0; c < C; ++c) acc[c] += wgt * gp[(size_t)c * VOX + o];
    };
    corner(i0[0], i0[1], i0[2], (1 - w[0]) * (1 - w[1]) * (1 - w[2]));
    corner(i1[0], i0[1], i0[2], w[0] * (1 - w[1]) * (1 - w[2]));
    corner(i0[0], i1[1], i0[2], (1 - w[0]) * w[1] * (1 - w[2]));
    corner(i1[0], i1[1], i0[2], w[0] * w[1] * (1 - w[2]));
    corner(i0[0], i0[1], i1[2], (1 - w[0]) * (1 - w[1]) * w[2]);
    corner(i1[0], i0[1], i1[2], w[0] * (1 - w[1]) * w[2]);
    corner(i0[0], i1[1], i1[2], (1 - w[0]) * w[1] * w[2]);
    corner(i1[0], i1[1], i1[2], w[0] * w[1] * w[2]);
    ++p;
  };
  gather(u[0], u[1], u[2]);
  float s[3], co[3];
#pragma unroll
  for (int d = 0; d < 3; ++d) { s[d] = sinf(u[d]); co[d] = cosf(u[d]); }
  for (int f = 0; f < 5; ++f) {
    gather(s[0], s[1], s[2]);
    gather(co[0], co[1], co[2]);
    if (f < 4) {
#pragma unroll
      for (int d = 0; d < 3; ++d) {
        float ns = 2.0f * s[d] * co[d];
        float nc = 1.0f - 2.0f * s[d] * s[d];
        s[d] = ns; co[d] = nc;
      }
    }
  }
  constexpr float inv = 1.0f / (float)P;
#pragma unroll
  for (int c = 0; c < C; ++c) out[(size_t)n * C + c] = acc[c] * inv;
}

extern "C" void kernel_launch(void* const* d_in, const int* in_sizes, int n_in,
                              void* d_out, int out_size, void* d_ws, size_t ws_size,
                              hipStream_t stream) {
  const float* xyz = (const float*)d_in[0];
  const float* grid = (const float*)d_in[1];
  const float* mn = (const float*)d_in[2];
  const float* mx = (const float*)d_in[3];
  float* out = (float*)d_out;
  int N = in_sizes[0] / 3;

  size_t gt_bytes = (size_t)P * VOX * C * sizeof(__half);   // ~233.6 MB
  size_t sorted_bytes = (size_t)N * sizeof(float4);         // 12.8 MB
  size_t cnt_bytes = (size_t)CELLS * sizeof(unsigned);      // 128 KB

  size_t need_sorted = sorted_bytes + gt_bytes + 2 * cnt_bytes + 1024;
  size_t need_min = gt_bytes + 256;

  int sblocks = (N + 255) / 256;
  int tblocks = (P * (VOX / 4) + 255) / 256;   // covers N too (2.43M > 800k)

  if (ws_size >= need_sorted) {
    char* w = (char*)d_ws;
    float4*   sorted  = (float4*)w;   w += sorted_bytes;
    __half*   gt      = (__half*)w;   w += gt_bytes;
    unsigned* counts  = (unsigned*)w; w += cnt_bytes;
    unsigned* offsets = (unsigned*)w;

    hipMemsetAsync(counts, 0, cnt_bytes, stream);
    transpose_count_kernel<<<tblocks, 256, 0, stream>>>(grid, gt, xyz, mn, mx,
                                                        counts, N);
    scan_kernel<<<1, 1024, 0, stream>>>(counts, offsets);
    scatter_kernel<<<sblocks, 256, 0, stream>>>(xyz, mn, mx, offsets, sorted, N);
    sample_sorted_kernel<<<sblocks, 256, 0, stream>>>(sorted, gt, out, N);
  } else if (ws_size >= need_min) {
    __half* gt = (__half*)d_ws;
    transpose_count_kernel<<<tblocks, 256, 0, stream>>>(grid, gt, xyz, mn, mx,
                                                        nullptr, 0);
    sample_fp16_kernel<<<sblocks, 256, 0, stream>>>(xyz, gt, mn, mx, out, N);
  } else {
    sample_naive_kernel<<<sblocks, 256, 0, stream>>>(xyz, grid, mn, mx, out, N);
  }
}